// Round 4
// baseline (128.290 us; speedup 1.0000x reference)
//
#include <hip/hip_runtime.h>
#include <cstdint>

#define TDIM 8192   // B_*S_ = 4*2048 flattened tokens
#define MDIM 1024   // in_features (GEMM K)
#define NDIM 1024   // out_features
#define KBITS 8
#define BK 64       // K-depth per staging iteration
#define TT 64       // t-tile (rows)
#define TN 128      // n-tile (cols)

typedef __bf16 bf16x8 __attribute__((ext_vector_type(8)));
typedef float f32x4 __attribute__((ext_vector_type(4)));

#define GAS(p) ((__attribute__((address_space(1))) void*)(uintptr_t)(p))
#define LAS(p) ((__attribute__((address_space(3))) void*)(uintptr_t)(p))

__device__ __forceinline__ unsigned short f2bf(float f) {
    union { float f; unsigned u; } v; v.f = f;
    unsigned r = v.u + 0x7fffu + ((v.u >> 16) & 1u);  // round-to-nearest-even
    return (unsigned short)(r >> 16);
}

// ---- fused prep ----
// blocks [0,1024): W-fold 32x32 tiles (dispatched FIRST so no serial tail):
//   Wt[n][m] = bf16( sum_k scale[k][n] * binary[k][m][n] ), k fully unrolled.
// blocks [1024,5120): x fp32 -> bf16 cast, 8 elems/thread, coalesced.
__global__ __launch_bounds__(256) void prep_kernel(const float* __restrict__ x,
                                                   unsigned short* __restrict__ xb,
                                                   const float* __restrict__ binary,
                                                   const float* __restrict__ scale,
                                                   unsigned short* __restrict__ wtr) {
    __shared__ float tile[32][33];
    const int tid = threadIdx.x;
    if (blockIdx.x >= 1024) {
        size_t idx = ((size_t)(blockIdx.x - 1024) * 256 + tid) * 8;
        float4 a = *(const float4*)(x + idx);
        float4 b = *(const float4*)(x + idx + 4);
        uint4 o;
        o.x = (unsigned)f2bf(a.x) | ((unsigned)f2bf(a.y) << 16);
        o.y = (unsigned)f2bf(a.z) | ((unsigned)f2bf(a.w) << 16);
        o.z = (unsigned)f2bf(b.x) | ((unsigned)f2bf(b.y) << 16);
        o.w = (unsigned)f2bf(b.z) | ((unsigned)f2bf(b.w) << 16);
        *(uint4*)(xb + idx) = o;
        return;
    }
    // ---- W-fold: 32x32 tile, thread owns (m-row r, 4 consecutive n) ----
    const int n0 = (blockIdx.x & 31) * 32;
    const int m0 = (blockIdx.x >> 5) * 32;
    const int r = tid >> 3;          // m offset 0..31
    const int cn = (tid & 7) * 4;    // n offset 0..28 step 4
    f32x4 acc = {0.f, 0.f, 0.f, 0.f};
#pragma unroll
    for (int k = 0; k < KBITS; ++k) {
        f32x4 v = *(const f32x4*)(binary + ((size_t)k * MDIM + m0 + r) * NDIM + n0 + cn);
        f32x4 s = *(const f32x4*)(scale + (size_t)k * NDIM + n0 + cn);
        acc += v * s;
    }
    // transpose through LDS: tile[n][m]
#pragma unroll
    for (int e = 0; e < 4; ++e) tile[cn + e][r] = acc[e];
    __syncthreads();
    const int rn = tid >> 3;
    const int cm = (tid & 7) * 4;
    ushort4 o4;
    o4.x = f2bf(tile[rn][cm + 0]);
    o4.y = f2bf(tile[rn][cm + 1]);
    o4.z = f2bf(tile[rn][cm + 2]);
    o4.w = f2bf(tile[rn][cm + 3]);
    *(ushort4*)(wtr + (size_t)(n0 + rn) * MDIM + m0 + cm) = o4;
}

// ---- gemm: out[t][n] = sum_m xb[t][m]*Wt[n][m] + bias[n] ----
// 64x128 tile, BK=64, grid 128x8 = 1024 blocks = 4 blocks/CU (the m97-ladder
// occupancy sweet spot: other blocks cover each block's barrier drain).
// 4 waves 2x2, wave = 32x64 via 2x4 MFMA 16x16x32 (x2 k-halves).
// blockIdx.x (=t) fastest: each XCD gets 16 t-strips x all n -> per-XCD
// working set = 2MB A-strip + 2MB B = 4MB = its L2. Staging is L2-hit.
__global__ __launch_bounds__(256, 4) void gemm_kernel(const unsigned short* __restrict__ xb,
                                                      const unsigned short* __restrict__ wtr,
                                                      const float* __restrict__ bias,
                                                      float* __restrict__ out) {
    __shared__ __attribute__((aligned(16))) unsigned short sA[TT * BK];
    __shared__ __attribute__((aligned(16))) unsigned short sB[TN * BK];

    const int tid = threadIdx.x;
    const int lane = tid & 63;
    const int wv = tid >> 6;
    const int wrow = wv >> 1;   // t half
    const int wcol = wv & 1;    // n half
    const int lrow = lane & 15;
    const int q = lane >> 4;

    const int t0 = blockIdx.x * TT;
    const int n0 = blockIdx.y * TN;

    // staging granules (16B = 8 bf16): A 64x8=512 (2/thread), B 128x8=1024 (4/thread).
    // LDS slot s = r*8+gs holds global granule gs^(r&7) of row r (XOR swizzle).
    const unsigned short* srcA[2];
    unsigned short* dstA[2];
#pragma unroll
    for (int j = 0; j < 2; ++j) {
        int s = tid + j * 256;
        int r = s >> 3;
        int g = (s & 7) ^ (r & 7);
        srcA[j] = xb + (size_t)(t0 + r) * MDIM + g * 8;
        dstA[j] = sA + s * 8;
    }
    const unsigned short* srcB[4];
    unsigned short* dstB[4];
#pragma unroll
    for (int j = 0; j < 4; ++j) {
        int s = tid + j * 256;
        int r = s >> 3;
        int g = (s & 7) ^ (r & 7);
        srcB[j] = wtr + (size_t)(n0 + r) * MDIM + g * 8;
        dstB[j] = sB + s * 8;
    }

    // fragment LDS offsets: row, k-half h, stored granule (h*4+q)^(row&7)
    int a_off[2][2], b_off[2][4];
#pragma unroll
    for (int h = 0; h < 2; ++h) {
#pragma unroll
        for (int i = 0; i < 2; ++i) {
            int m = wrow * 32 + i * 16 + lrow;
            a_off[h][i] = (m * 8 + ((h * 4 + q) ^ (m & 7))) * 8;
        }
#pragma unroll
        for (int j = 0; j < 4; ++j) {
            int n = wcol * 64 + j * 16 + lrow;
            b_off[h][j] = (n * 8 + ((h * 4 + q) ^ (n & 7))) * 8;
        }
    }

    f32x4 acc[2][4];
    const f32x4 zero = {0.f, 0.f, 0.f, 0.f};
#pragma unroll
    for (int i = 0; i < 2; ++i)
#pragma unroll
        for (int j = 0; j < 4; ++j) acc[i][j] = zero;

    for (int k0 = 0; k0 < MDIM; k0 += BK) {
#pragma unroll
        for (int j = 0; j < 2; ++j)
            __builtin_amdgcn_global_load_lds(GAS(srcA[j] + k0), LAS(dstA[j]), 16, 0, 0);
#pragma unroll
        for (int j = 0; j < 4; ++j)
            __builtin_amdgcn_global_load_lds(GAS(srcB[j] + k0), LAS(dstB[j]), 16, 0, 0);
        __syncthreads();

#pragma unroll
        for (int h = 0; h < 2; ++h) {
            bf16x8 af[2], bfr[4];
#pragma unroll
            for (int i = 0; i < 2; ++i) af[i] = *(const bf16x8*)(sA + a_off[h][i]);
#pragma unroll
            for (int j = 0; j < 4; ++j) bfr[j] = *(const bf16x8*)(sB + b_off[h][j]);
#pragma unroll
            for (int i = 0; i < 2; ++i)
#pragma unroll
                for (int j = 0; j < 4; ++j)
                    acc[i][j] = __builtin_amdgcn_mfma_f32_16x16x32_bf16(af[i], bfr[j],
                                                                        acc[i][j], 0, 0, 0);
        }
        __syncthreads();
    }

    // epilogue: C/D layout col=lane&15 (n), row=q*4+reg (t). fuse bias.
#pragma unroll
    for (int j = 0; j < 4; ++j) {
        const int n = n0 + wcol * 64 + j * 16 + lrow;
        const float bv = bias[n];
#pragma unroll
        for (int i = 0; i < 2; ++i) {
            const int tb = t0 + wrow * 32 + i * 16 + q * 4;
#pragma unroll
            for (int r = 0; r < 4; ++r) {
                out[(size_t)(tb + r) * NDIM + n] = acc[i][j][r] + bv;
            }
        }
    }
}

extern "C" void kernel_launch(void* const* d_in, const int* in_sizes, int n_in,
                              void* d_out, int out_size, void* d_ws, size_t ws_size,
                              hipStream_t stream) {
    const float* x      = (const float*)d_in[0];   // [4,2048,1024] fp32
    const float* binary = (const float*)d_in[1];   // [8,1024,1024] fp32 (+/-1)
    const float* scale  = (const float*)d_in[2];   // [8,1,1024] fp32
    const float* bias   = (const float*)d_in[3];   // [1024] fp32
    float* out = (float*)d_out;                    // [4,2048,1024] fp32

    unsigned short* xb  = (unsigned short*)d_ws;            // 16 MB bf16 x
    unsigned short* wtr = xb + (size_t)TDIM * MDIM;         // 2 MB bf16 Wt[n][m]

    prep_kernel<<<1024 + 4096, 256, 0, stream>>>(x, xb, binary, scale, wtr);
    gemm_kernel<<<dim3(TDIM / TT, NDIM / TN), 256, 0, stream>>>(xb, wtr, bias, out);
}

// Round 5
// 128.025 us; speedup vs baseline: 1.0021x; 1.0021x over previous
//
#include <hip/hip_runtime.h>
#include <cstdint>

#define TDIM 8192   // B_*S_ = 4*2048 flattened tokens
#define MDIM 1024   // in_features (GEMM K)
#define NDIM 1024   // out_features
#define KBITS 8
#define BK 64       // K-depth per staging iteration
#define TT 64       // t-tile (rows)
#define TN 128      // n-tile (cols)

typedef __bf16 bf16x8 __attribute__((ext_vector_type(8)));
typedef float f32x4 __attribute__((ext_vector_type(4)));
typedef float f32x16 __attribute__((ext_vector_type(16)));

#define GAS(p) ((__attribute__((address_space(1))) void*)(uintptr_t)(p))
#define LAS(p) ((__attribute__((address_space(3))) void*)(uintptr_t)(p))

__device__ __forceinline__ unsigned short f2bf(float f) {
    union { float f; unsigned u; } v; v.f = f;
    unsigned r = v.u + 0x7fffu + ((v.u >> 16) & 1u);  // round-to-nearest-even
    return (unsigned short)(r >> 16);
}

// ---- fused prep ----
// blocks [0,1024): W-fold 32x32 tiles (dispatched FIRST so no serial tail):
//   Wt[n][m] = bf16( sum_k scale[k][n] * binary[k][m][n] ), k fully unrolled.
// blocks [1024,5120): x fp32 -> bf16 cast, 8 elems/thread, coalesced.
__global__ __launch_bounds__(256) void prep_kernel(const float* __restrict__ x,
                                                   unsigned short* __restrict__ xb,
                                                   const float* __restrict__ binary,
                                                   const float* __restrict__ scale,
                                                   unsigned short* __restrict__ wtr) {
    __shared__ float tile[32][33];
    const int tid = threadIdx.x;
    if (blockIdx.x >= 1024) {
        size_t idx = ((size_t)(blockIdx.x - 1024) * 256 + tid) * 8;
        float4 a = *(const float4*)(x + idx);
        float4 b = *(const float4*)(x + idx + 4);
        uint4 o;
        o.x = (unsigned)f2bf(a.x) | ((unsigned)f2bf(a.y) << 16);
        o.y = (unsigned)f2bf(a.z) | ((unsigned)f2bf(a.w) << 16);
        o.z = (unsigned)f2bf(b.x) | ((unsigned)f2bf(b.y) << 16);
        o.w = (unsigned)f2bf(b.z) | ((unsigned)f2bf(b.w) << 16);
        *(uint4*)(xb + idx) = o;
        return;
    }
    // ---- W-fold: 32x32 tile, thread owns (m-row r, 4 consecutive n) ----
    const int n0 = (blockIdx.x & 31) * 32;
    const int m0 = (blockIdx.x >> 5) * 32;
    const int r = tid >> 3;          // m offset 0..31
    const int cn = (tid & 7) * 4;    // n offset 0..28 step 4
    f32x4 acc = {0.f, 0.f, 0.f, 0.f};
#pragma unroll
    for (int k = 0; k < KBITS; ++k) {
        f32x4 v = *(const f32x4*)(binary + ((size_t)k * MDIM + m0 + r) * NDIM + n0 + cn);
        f32x4 s = *(const f32x4*)(scale + (size_t)k * NDIM + n0 + cn);
        acc += v * s;
    }
    // transpose through LDS: tile[n][m]
#pragma unroll
    for (int e = 0; e < 4; ++e) tile[cn + e][r] = acc[e];
    __syncthreads();
    const int rn = tid >> 3;
    const int cm = (tid & 7) * 4;
    ushort4 o4;
    o4.x = f2bf(tile[rn][cm + 0]);
    o4.y = f2bf(tile[rn][cm + 1]);
    o4.z = f2bf(tile[rn][cm + 2]);
    o4.w = f2bf(tile[rn][cm + 3]);
    *(ushort4*)(wtr + (size_t)(n0 + rn) * MDIM + m0 + cm) = o4;
}

// ---- gemm: out[t][n] = sum_m xb[t][m]*Wt[n][m] + bias[n] ----
// 64x128 tile, BK=64, grid 128x8 = 1024 blocks = 4 blocks/CU.
// Inner math: v_mfma_f32_32x32x16_bf16 (2382 TF ubench vs 2075 for 16x16x32;
// half the MFMA issue slots for the same FLOPs). 4 waves 2x2: wave = 32(t)x64(n)
// = 2 MFMAs per k16-chunk, acc 2x f32x16 (32 VGPRs, same as before).
// A-operand layout: A[m=lane&31][k=(lane>>5)*8+j] -> one ds_read_b128/lane from
// the same 8x16B-granule XOR-swizzled rows used for staging (machinery unchanged).
__global__ __launch_bounds__(256, 4) void gemm_kernel(const unsigned short* __restrict__ xb,
                                                      const unsigned short* __restrict__ wtr,
                                                      const float* __restrict__ bias,
                                                      float* __restrict__ out) {
    __shared__ __attribute__((aligned(16))) unsigned short sA[TT * BK];
    __shared__ __attribute__((aligned(16))) unsigned short sB[TN * BK];

    const int tid = threadIdx.x;
    const int lane = tid & 63;
    const int wv = tid >> 6;
    const int wrow = wv >> 1;    // t 32-tile 0..1
    const int wcol = wv & 1;     // n half 0..1
    const int lr = lane & 31;    // row within 32-tile
    const int half = lane >> 5;  // k-half selector

    const int t0 = blockIdx.x * TT;
    const int n0 = blockIdx.y * TN;

    // staging granules (16B = 8 bf16): A 64x8=512 (2/thread), B 128x8=1024 (4/thread).
    // LDS slot s = r*8+gs holds global granule gs^(r&7) of row r (XOR swizzle).
    const unsigned short* srcA[2];
    unsigned short* dstA[2];
#pragma unroll
    for (int j = 0; j < 2; ++j) {
        int s = tid + j * 256;
        int r = s >> 3;
        int g = (s & 7) ^ (r & 7);
        srcA[j] = xb + (size_t)(t0 + r) * MDIM + g * 8;
        dstA[j] = sA + s * 8;
    }
    const unsigned short* srcB[4];
    unsigned short* dstB[4];
#pragma unroll
    for (int j = 0; j < 4; ++j) {
        int s = tid + j * 256;
        int r = s >> 3;
        int g = (s & 7) ^ (r & 7);
        srcB[j] = wtr + (size_t)(n0 + r) * MDIM + g * 8;
        dstB[j] = sB + s * 8;
    }

    // fragment LDS offsets: k-chunk c (K=16), granule g = c*2 + half, XOR row swizzle
    int a_off[4], b_off[4][2];
#pragma unroll
    for (int c = 0; c < 4; ++c) {
        int m = wrow * 32 + lr;
        a_off[c] = (m * 8 + ((c * 2 + half) ^ (m & 7))) * 8;
#pragma unroll
        for (int j = 0; j < 2; ++j) {
            int n = wcol * 64 + j * 32 + lr;
            b_off[c][j] = (n * 8 + ((c * 2 + half) ^ (n & 7))) * 8;
        }
    }

    f32x16 acc[2];
#pragma unroll
    for (int j = 0; j < 2; ++j)
#pragma unroll
        for (int r = 0; r < 16; ++r) acc[j][r] = 0.f;

    for (int k0 = 0; k0 < MDIM; k0 += BK) {
#pragma unroll
        for (int j = 0; j < 2; ++j)
            __builtin_amdgcn_global_load_lds(GAS(srcA[j] + k0), LAS(dstA[j]), 16, 0, 0);
#pragma unroll
        for (int j = 0; j < 4; ++j)
            __builtin_amdgcn_global_load_lds(GAS(srcB[j] + k0), LAS(dstB[j]), 16, 0, 0);
        __syncthreads();

#pragma unroll
        for (int c = 0; c < 4; ++c) {
            bf16x8 af = *(const bf16x8*)(sA + a_off[c]);
            bf16x8 b0 = *(const bf16x8*)(sB + b_off[c][0]);
            bf16x8 b1 = *(const bf16x8*)(sB + b_off[c][1]);
            acc[0] = __builtin_amdgcn_mfma_f32_32x32x16_bf16(af, b0, acc[0], 0, 0, 0);
            acc[1] = __builtin_amdgcn_mfma_f32_32x32x16_bf16(af, b1, acc[1], 0, 0, 0);
        }
        __syncthreads();
    }

    // epilogue: C/D layout col(n)=lane&31, row(t)=(reg&3)+8*(reg>>2)+4*half. fuse bias.
#pragma unroll
    for (int j = 0; j < 2; ++j) {
        const int n = n0 + wcol * 64 + j * 32 + lr;
        const float bv = bias[n];
#pragma unroll
        for (int r = 0; r < 16; ++r) {
            const int t = t0 + wrow * 32 + (r & 3) + 8 * (r >> 2) + 4 * half;
            out[(size_t)t * NDIM + n] = acc[j][r] + bv;
        }
    }
}

extern "C" void kernel_launch(void* const* d_in, const int* in_sizes, int n_in,
                              void* d_out, int out_size, void* d_ws, size_t ws_size,
                              hipStream_t stream) {
    const float* x      = (const float*)d_in[0];   // [4,2048,1024] fp32
    const float* binary = (const float*)d_in[1];   // [8,1024,1024] fp32 (+/-1)
    const float* scale  = (const float*)d_in[2];   // [8,1,1024] fp32
    const float* bias   = (const float*)d_in[3];   // [1024] fp32
    float* out = (float*)d_out;                    // [4,2048,1024] fp32

    unsigned short* xb  = (unsigned short*)d_ws;            // 16 MB bf16 x
    unsigned short* wtr = xb + (size_t)TDIM * MDIM;         // 2 MB bf16 Wt[n][m]

    prep_kernel<<<1024 + 4096, 256, 0, stream>>>(x, xb, binary, scale, wtr);
    gemm_kernel<<<dim3(TDIM / TT, NDIM / TN), 256, 0, stream>>>(xb, wtr, bias, out);
}